// Round 1
// baseline (163.469 us; speedup 1.0000x reference)
//
#include <hip/hip_runtime.h>
#include <cstddef>

namespace {
constexpr int Z    = 4;
constexpr int N    = 256;
constexpr int CIN  = 32;
constexpr int COUT = 32;
constexpr int HID  = 64;
constexpr int OC   = COUT * CIN;  // 1024
}

// ---------------------------------------------------------------------------
// Kernel A: M[z][b][i][h] = sum_j W2[h][i*32+j] * f[z][b][j]
//           bf[z][b][i]   = sum_j b2[i*32+j]   * f[z][b][j]
// 256 blocks (z, group-of-4 b), 256 threads. W2 stays L2-resident (256 KiB),
// each row segment reused across 4 b's.
// ---------------------------------------------------------------------------
__global__ __launch_bounds__(256) void precompute_M(
    const float* __restrict__ features,
    const float* __restrict__ W2,
    const float* __restrict__ b2,
    float* __restrict__ Mws,
    float* __restrict__ bfws)
{
    __shared__ __align__(16) float f_lds[4 * CIN];
    const int blk = blockIdx.x;          // Z * 64 = 256
    const int z   = blk >> 6;
    const int b0  = (blk & 63) << 2;
    const int t   = threadIdx.x;

    if (t < 4 * CIN) f_lds[t] = features[(z * N + b0) * CIN + t];
    __syncthreads();

    const float4* f4 = reinterpret_cast<const float4*>(f_lds);  // [4][8]

#pragma unroll
    for (int p = 0; p < 8; ++p) {
        const int idx = p * 256 + t;     // 0..2047 -> (i, h)
        const int i   = idx >> 6;
        const int hh  = idx & 63;
        const float4* w2r = reinterpret_cast<const float4*>(W2 + hh * OC + i * CIN);
        float4 w[8];
#pragma unroll
        for (int q = 0; q < 8; ++q) w[q] = w2r[q];
#pragma unroll
        for (int bl = 0; bl < 4; ++bl) {
            float v = 0.f;
#pragma unroll
            for (int q = 0; q < 8; ++q) {
                const float4 f = f4[bl * 8 + q];
                v += w[q].x * f.x + w[q].y * f.y + w[q].z * f.z + w[q].w * f.w;
            }
            Mws[(size_t)((z * N + b0 + bl) * COUT + i) * HID + hh] = v;
        }
    }

    if (t < 128) {  // bf for 4 b's x 32 i
        const int bl = t >> 5, i = t & 31;
        const float4* b2r = reinterpret_cast<const float4*>(b2 + i * CIN);
        float v = 0.f;
#pragma unroll
        for (int q = 0; q < 8; ++q) {
            const float4 bb = b2r[q];
            const float4 f  = f4[bl * 8 + q];
            v += bb.x * f.x + bb.y * f.y + bb.z * f.z + bb.w * f.w;
        }
        bfws[(z * N + b0 + bl) * COUT + i] = v;
    }
}

// ---------------------------------------------------------------------------
// Kernel B: one block per (z, b). Per block:
//   H[a][h] = relu((g[z,b]-g[z,a]) @ W1 + b1)   (256 x 64, LDS, stride 68)
//   OUT[a][i] = sum_h H[a][h] * M[z,b,i,h] + bf[z,b,i]   (256x32x64 GEMM)
// Thread tile: 8 a x 4 i (32 acc), ds_read_b128 fragments.
// Epilogue: transpose through LDS so global stores are contiguous float4.
// ---------------------------------------------------------------------------
__global__ __launch_bounds__(256, 2) void pair_contract(
    const float* __restrict__ geometry,
    const float* __restrict__ W1,
    const float* __restrict__ b1,
    const float* __restrict__ Mws,
    const float* __restrict__ bfws,
    float* __restrict__ out)
{
    // Hs: H[a][h] stride 68 (69632 B); reused as out staging [a][i] stride 36.
    __shared__ __align__(16) float Hs[N * 68];
    __shared__ __align__(16) float Ml[COUT * HID];   // M[i][h], 8 KiB
    __shared__ __align__(16) float w1l[3 * HID];
    __shared__ __align__(16) float b1l[HID];
    __shared__ __align__(16) float bfl[COUT];

    const int blk = blockIdx.x;   // Z*N = 1024
    const int z = blk >> 8;
    const int b = blk & 255;
    const int t = threadIdx.x;

    if (t < HID) {
        w1l[t]           = W1[t];
        w1l[HID + t]     = W1[HID + t];
        w1l[2 * HID + t] = W1[2 * HID + t];
        b1l[t]           = b1[t];
    }
    if (t < COUT) bfl[t] = bfws[(z * N + b) * COUT + t];
    {
        const float4* Ms = reinterpret_cast<const float4*>(
            Mws + (size_t)(z * N + b) * (COUT * HID));
        float4* Ml4 = reinterpret_cast<float4*>(Ml);
        Ml4[t]       = Ms[t];
        Ml4[t + 256] = Ms[t + 256];
    }
    const float gbx = geometry[(z * N + b) * 3 + 0];
    const float gby = geometry[(z * N + b) * 3 + 1];
    const float gbz = geometry[(z * N + b) * 3 + 2];
    const float gax = geometry[(z * N + t) * 3 + 0];
    const float gay = geometry[(z * N + t) * 3 + 1];
    const float gaz = geometry[(z * N + t) * 3 + 2];
    const float dx = gbx - gax, dy = gby - gay, dz = gbz - gaz;  // g[b] - g[a]
    __syncthreads();

    // H row a = t (thread-private diff), 64 h values, float4 LDS writes.
#pragma unroll
    for (int k = 0; k < HID; k += 4) {
        const float4 w0 = *reinterpret_cast<const float4*>(&w1l[k]);
        const float4 w1v = *reinterpret_cast<const float4*>(&w1l[HID + k]);
        const float4 w2v = *reinterpret_cast<const float4*>(&w1l[2 * HID + k]);
        const float4 bb = *reinterpret_cast<const float4*>(&b1l[k]);
        float4 h;
        h.x = fmaxf(dx * w0.x + dy * w1v.x + dz * w2v.x + bb.x, 0.f);
        h.y = fmaxf(dx * w0.y + dy * w1v.y + dz * w2v.y + bb.y, 0.f);
        h.z = fmaxf(dx * w0.z + dy * w1v.z + dz * w2v.z + bb.z, 0.f);
        h.w = fmaxf(dx * w0.w + dy * w1v.w + dz * w2v.w + bb.w, 0.f);
        *reinterpret_cast<float4*>(&Hs[t * 68 + k]) = h;
    }
    __syncthreads();

    const int a_thr = t & 31;     // a base lane
    const int i_thr = t >> 5;     // 0..7 -> i = i_thr*4 + v
    float acc[8][4];
#pragma unroll
    for (int u = 0; u < 8; ++u)
#pragma unroll
        for (int v = 0; v < 4; ++v) acc[u][v] = bfl[i_thr * 4 + v];

#pragma unroll
    for (int k4 = 0; k4 < 16; ++k4) {
        float4 m[4];
#pragma unroll
        for (int v = 0; v < 4; ++v)
            m[v] = *reinterpret_cast<const float4*>(&Ml[(i_thr * 4 + v) * HID + k4 * 4]);
#pragma unroll
        for (int u = 0; u < 8; ++u) {
            const float4 h = *reinterpret_cast<const float4*>(
                &Hs[(a_thr + 32 * u) * 68 + k4 * 4]);
#pragma unroll
            for (int v = 0; v < 4; ++v)
                acc[u][v] += h.x * m[v].x + h.y * m[v].y + h.z * m[v].z + h.w * m[v].w;
        }
    }
    __syncthreads();

    // Stage OUT[a][i] in LDS (stride 36 floats: bank-balanced, 16B aligned).
#pragma unroll
    for (int u = 0; u < 8; ++u) {
        float4 o;
        o.x = acc[u][0]; o.y = acc[u][1]; o.z = acc[u][2]; o.w = acc[u][3];
        *reinterpret_cast<float4*>(&Hs[(a_thr + 32 * u) * 36 + i_thr * 4]) = o;
    }
    __syncthreads();

    // Coalesced global write: consecutive lanes cover (a, i-quad) with i fastest;
    // each a-row is 128 B contiguous at ((z*N+a)*N+b)*32.
#pragma unroll
    for (int r = 0; r < 8; ++r) {
        const int c  = r * 256 + t;   // 0..2047
        const int a  = c >> 3;
        const int i4 = c & 7;
        const float4 val = *reinterpret_cast<const float4*>(&Hs[a * 36 + i4 * 4]);
        *reinterpret_cast<float4*>(
            &out[(((size_t)z * N + a) * N + b) * COUT + i4 * 4]) = val;
    }
}

extern "C" void kernel_launch(void* const* d_in, const int* in_sizes, int n_in,
                              void* d_out, int out_size, void* d_ws, size_t ws_size,
                              hipStream_t stream) {
    const float* features = (const float*)d_in[0];
    const float* geometry = (const float*)d_in[1];
    const float* W1 = (const float*)d_in[2];
    const float* b1 = (const float*)d_in[3];
    const float* W2 = (const float*)d_in[4];
    const float* b2 = (const float*)d_in[5];
    float* out = (float*)d_out;

    float* Mws  = (float*)d_ws;                          // Z*N*COUT*HID = 2,097,152 floats
    float* bfws = Mws + (size_t)Z * N * COUT * HID;      // + Z*N*COUT  = 32,768 floats

    precompute_M<<<Z * (N / 4), 256, 0, stream>>>(features, W2, b2, Mws, bfws);
    pair_contract<<<Z * N, 256, 0, stream>>>(geometry, W1, b1, Mws, bfws, out);
}